// Round 1
// 364.583 us; speedup vs baseline: 1.0582x; 1.0582x over previous
//
#include <hip/hip_runtime.h>
#include <hip/hip_bf16.h>
#include <cstdint>
#include <cstddef>

#define B_ 4
#define S_ 2048
#define E_ 1024
#define H_ 16
#define D_ 64
#define NEG_BIG (-1e30f)
#define SC2 0.18033688011112043f   /* 0.125 * log2(e) */

typedef __bf16 bf16x8 __attribute__((ext_vector_type(8)));
typedef __bf16 bf16x4v __attribute__((ext_vector_type(4)));
typedef float f32x4 __attribute__((ext_vector_type(4)));
typedef float f32x16 __attribute__((ext_vector_type(16)));

__device__ __forceinline__ void async_copy16(void* lds, const void* g) {
  __builtin_amdgcn_global_load_lds(
      (const __attribute__((address_space(1))) void*)g,
      (__attribute__((address_space(3))) void*)lds, 16, 0, 0);
}

__device__ __forceinline__ float bfu2f(unsigned short u) {
  unsigned v = ((unsigned)u) << 16;
  float f;
  __builtin_memcpy(&f, &v, 4);
  return f;
}
__device__ __forceinline__ unsigned short f2bfu(float f) {
  __hip_bfloat16 h = __float2bfloat16(f);  // RNE
  unsigned short u;
  __builtin_memcpy(&u, &h, 2);
  return u;
}
__device__ __forceinline__ unsigned pk2(float a, float b) {
  return (unsigned)f2bfu(a) | ((unsigned)f2bfu(b) << 16);
}

// swap hi 32 lanes of a with lo 32 lanes of b (v_permlane32_swap_b32)
__device__ __forceinline__ void pl32swap(unsigned& a, unsigned& b) {
#if defined(__has_builtin)
#if __has_builtin(__builtin_amdgcn_permlane32_swap)
  typedef int i32x2 __attribute__((ext_vector_type(2)));
  i32x2 r = __builtin_amdgcn_permlane32_swap((int)a, (int)b, false, false);
  a = (unsigned)r[0];
  b = (unsigned)r[1];
  return;
#else
  asm("v_permlane32_swap_b32 %0, %1" : "+v"(a), "+v"(b));
  return;
#endif
#else
  asm("v_permlane32_swap_b32 %0, %1" : "+v"(a), "+v"(b));
#endif
}

// ---------------- dtype probe (proven) ----------------
__global__ __launch_bounds__(256) void probe_dtype(
    const unsigned short* __restrict__ xr, int* __restrict__ flagp) {
  __shared__ int cnt;
  if (threadIdx.x == 0) cnt = 0;
  __syncthreads();
  int bad = 0;
  for (int i = 0; i < 32; ++i) {
    unsigned short u = xr[(threadIdx.x * 32 + i) * 2];
    int e = (u >> 7) & 0xFF;
    if (e == 0xFF || e >= 0x90 || (e != 0 && e <= 0x60)) bad++;
  }
  atomicAdd(&cnt, bad);
  __syncthreads();
  if (threadIdx.x == 0) {
    flagp[0] = (cnt > 512) ? 0 : 1;  // 0=fp32, 1=bf16
    flagp[1] = 1;                    // all-ones-mask flag, cleared by mask_bias
  }
}

__global__ __launch_bounds__(256) void convert_to_f32(
    const void* __restrict__ in, float* __restrict__ out,
    const int* __restrict__ flagp, int n) {
  int i = blockIdx.x * blockDim.x + threadIdx.x;
  if (i >= n) return;
  out[i] = (*flagp == 0) ? ((const float*)in)[i]
                         : bfu2f(((const unsigned short*)in)[i]);
}

// pad mask -> additive bias (0 / -1e30); also detect all-ones mask
__global__ __launch_bounds__(256) void mask_bias(
    const int* __restrict__ am, float* __restrict__ mb,
    int* __restrict__ flagp, int n) {
  int i = blockIdx.x * blockDim.x + threadIdx.x;
  if (i < n) {
    int a = am[i];
    mb[i] = a ? 0.f : NEG_BIG;
    if (a == 0) atomicAnd(flagp + 1, 0);
  }
}

// transpose + convert: out_bf16[C][R] = in[R][C]   (proven)
__global__ __launch_bounds__(256) void transpose_conv(
    const void* __restrict__ in, unsigned short* __restrict__ out,
    const int* __restrict__ flagp, int R, int C) {
  __shared__ unsigned short t[32][33];
  const int flag = *flagp;
  const int c0 = blockIdx.x * 32, r0 = blockIdx.y * 32;
  const int lc = threadIdx.x & 31, lr = threadIdx.x >> 5;
  for (int i = 0; i < 4; ++i) {
    int r = lr + i * 8;
    size_t idx = (size_t)(r0 + r) * C + c0 + lc;
    t[r][lc] = (flag == 0) ? f2bfu(((const float*)in)[idx])
                           : ((const unsigned short*)in)[idx];
  }
  __syncthreads();
  for (int i = 0; i < 4; ++i) {
    int r = lr + i * 8;
    out[(size_t)(c0 + r) * R + r0 + lc] = t[lc][r];
  }
}

// -------- GEMM1: qkv = x(fp32|bf16) @ WqkvT^T + bias, out bf16 --------
__global__ __launch_bounds__(256) void gemm_x_w(
    const void* __restrict__ Xin, long long xoff,
    const __hip_bfloat16* __restrict__ Bt,
    const float* __restrict__ bias,
    const int* __restrict__ flagp,
    __hip_bfloat16* __restrict__ C,
    int M, int N, int K) {
  __shared__ __align__(16) __hip_bfloat16 As[128 * 32];
  __shared__ __align__(16) __hip_bfloat16 Bs[128 * 32];
  const int flag = *flagp;
  const int tid = threadIdx.x;
  const int m0 = blockIdx.x * 128, n0 = blockIdx.y * 128;
  const int w = tid >> 6, lane = tid & 63;
  const int wm = (w & 1) * 64, wn = (w >> 1) * 64;
  const int lm = lane & 15, kg = lane >> 4;
  const int e0 = tid * 8, e1 = tid * 8 + 2048;
  const int ra = tid >> 2;
  const int sw = ((tid >> 3) & 3);
  const int ca = ((tid & 3) ^ sw) * 8;

  f32x4 acc[4][4] = {};

  for (int k0 = 0; k0 < K; k0 += 32) {
    uint4 aw0, aw1;
    if (flag == 0) {
      const float* A32 = (const float*)Xin + xoff;
      float4 f0 = *(const float4*)(A32 + (size_t)(m0 + ra) * K + k0 + ca);
      float4 f1 = *(const float4*)(A32 + (size_t)(m0 + ra) * K + k0 + ca + 4);
      float4 f2 = *(const float4*)(A32 + (size_t)(m0 + ra + 64) * K + k0 + ca);
      float4 f3 = *(const float4*)(A32 + (size_t)(m0 + ra + 64) * K + k0 + ca + 4);
      aw0 = make_uint4(pk2(f0.x, f0.y), pk2(f0.z, f0.w), pk2(f1.x, f1.y), pk2(f1.z, f1.w));
      aw1 = make_uint4(pk2(f2.x, f2.y), pk2(f2.z, f2.w), pk2(f3.x, f3.y), pk2(f3.z, f3.w));
    } else {
      const unsigned short* A16 = (const unsigned short*)Xin + xoff;
      aw0 = *(const uint4*)(A16 + (size_t)(m0 + ra) * K + k0 + ca);
      aw1 = *(const uint4*)(A16 + (size_t)(m0 + ra + 64) * K + k0 + ca);
    }
    __syncthreads();
    *(uint4*)(As + e0) = aw0;
    *(uint4*)(As + e1) = aw1;
    for (int c = 0; c < 2; ++c) {
      int o = tid * 16 + c * 4096;
      int row = o >> 6, chp = (o >> 4) & 3;
      int gch = chp ^ ((row >> 1) & 3);
      async_copy16((char*)Bs + o, (const char*)(Bt + (size_t)(n0 + row) * K + k0 + gch * 8));
    }
    __syncthreads();
    bf16x8 af[4], bfrag[4];
    for (int t = 0; t < 4; ++t) {
      int rt = wm + t * 16 + lm;
      int ch = kg ^ ((rt >> 1) & 3);
      af[t] = *(const bf16x8*)(As + rt * 32 + ch * 8);
    }
    for (int t = 0; t < 4; ++t) {
      int rt = wn + t * 16 + lm;
      int ch = kg ^ ((rt >> 1) & 3);
      bfrag[t] = *(const bf16x8*)(Bs + rt * 32 + ch * 8);
    }
    for (int tm = 0; tm < 4; ++tm)
      for (int tn = 0; tn < 4; ++tn)
        acc[tm][tn] = __builtin_amdgcn_mfma_f32_16x16x32_bf16(af[tm], bfrag[tn], acc[tm][tn], 0, 0, 0);
  }

  for (int tn = 0; tn < 4; ++tn) {
    int col = n0 + wn + tn * 16 + lm;
    float bv = bias[col];
    for (int tm = 0; tm < 4; ++tm) {
      int rbase = m0 + wm + tm * 16 + kg * 4;
      for (int r = 0; r < 4; ++r)
        C[(size_t)(rbase + r) * N + col] = __float2bfloat16(acc[tm][tn][r] + bv);
    }
  }
}

// -------- GEMM2: out = attno @ WprojT^T + bias; out dtype by flag --------
__global__ __launch_bounds__(256) void gemm_p_out(
    const __hip_bfloat16* __restrict__ A,
    const __hip_bfloat16* __restrict__ Bt,
    const float* __restrict__ bias,
    const int* __restrict__ flagp,
    void* __restrict__ Cv, long long coff,
    int M, int N, int K) {
  __shared__ __align__(16) __hip_bfloat16 As[128 * 32];
  __shared__ __align__(16) __hip_bfloat16 Bs[128 * 32];
  const int flag = *flagp;
  const int tid = threadIdx.x;
  const int m0 = blockIdx.x * 128, n0 = blockIdx.y * 128;
  const int w = tid >> 6, lane = tid & 63;
  const int wm = (w & 1) * 64, wn = (w >> 1) * 64;
  const int lm = lane & 15, kg = lane >> 4;

  f32x4 acc[4][4] = {};

  for (int k0 = 0; k0 < K; k0 += 32) {
    __syncthreads();
    for (int c = 0; c < 2; ++c) {
      int o = tid * 16 + c * 4096;
      int row = o >> 6, chp = (o >> 4) & 3;
      int gch = chp ^ ((row >> 1) & 3);
      async_copy16((char*)As + o, (const char*)(A + (size_t)(m0 + row) * K + k0 + gch * 8));
      async_copy16((char*)Bs + o, (const char*)(Bt + (size_t)(n0 + row) * K + k0 + gch * 8));
    }
    __syncthreads();
    bf16x8 af[4], bfrag[4];
    for (int t = 0; t < 4; ++t) {
      int rt = wm + t * 16 + lm;
      int ch = kg ^ ((rt >> 1) & 3);
      af[t] = *(const bf16x8*)(As + rt * 32 + ch * 8);
    }
    for (int t = 0; t < 4; ++t) {
      int rt = wn + t * 16 + lm;
      int ch = kg ^ ((rt >> 1) & 3);
      bfrag[t] = *(const bf16x8*)(Bs + rt * 32 + ch * 8);
    }
    for (int tm = 0; tm < 4; ++tm)
      for (int tn = 0; tn < 4; ++tn)
        acc[tm][tn] = __builtin_amdgcn_mfma_f32_16x16x32_bf16(af[tm], bfrag[tn], acc[tm][tn], 0, 0, 0);
  }

  for (int tn = 0; tn < 4; ++tn) {
    int col = n0 + wn + tn * 16 + lm;
    float bv = bias[col];
    for (int tm = 0; tm < 4; ++tm) {
      int rbase = m0 + wm + tm * 16 + kg * 4;
      for (int r = 0; r < 4; ++r) {
        float v = acc[tm][tn][r] + bv;
        size_t idx = (size_t)coff + (size_t)(rbase + r) * N + col;
        if (flag == 0) ((float*)Cv)[idx] = v;
        else           ((unsigned short*)Cv)[idx] = f2bfu(v);
      }
    }
  }
}

// -------- causal flash attention v4: 32x32 MFMA, in-register P exchange ----
// 512 threads (8 waves), 256 q/block (32 q/wave), 64-key tiles, double-
// buffered K/V, one barrier/tile.  S^T = K·Q^T via mfma_32x32x16 so each
// lane holds P[key...][q=lane&31]; the P->PV operand motion is 4
// v_permlane32_swap per 32-key subtile (no P LDS buffer at all).
// Defer-max rescale (THR=8), all-ones-mask fast path, s_setprio on MFMA.
#define VSTR 72
__global__ __launch_bounds__(512, 4) void attn_flash(
    const __hip_bfloat16* __restrict__ qkv,  // [bsz*S][3072]
    const float* __restrict__ mbias,         // [bsz*S] 0 / -1e30
    const int* __restrict__ flags,           // flags[1]: mask all-ones
    __hip_bfloat16* __restrict__ outp) {     // [bsz*S][1024]
  __shared__ __align__(16) __hip_bfloat16 Ks[2][64 * 64];   // [key][d], XOR-swizzled
  __shared__ __align__(16) __hip_bfloat16 VT[2][64 * VSTR]; // [d][key]

  const int tid = threadIdx.x;
  const int qt = (gridDim.x - 1) - blockIdx.x;   // LPT: heavy first
  const int bh = blockIdx.y;
  const int b = bh >> 4, h = bh & 15;
  const int q0 = qt * 256;
  const size_t rowbase = (size_t)b * S_;
  const int w = tid >> 6, lane = tid & 63;
  const int l31 = lane & 31, hi = lane >> 5;
  const int qg = q0 + w * 32 + l31;
  const int wq_min = q0 + w * 32, wq_max = wq_min + 31;
  const int allones = flags[1];

  // K staging geometry (swizzled source)
  const int krow = tid >> 3;
  const int kgch = (tid & 7) ^ (krow & 7);

  // Q fragments: B[k=d][n=q]; lane holds Q[qg][kc*16 + hi*8 + e]
  bf16x8 bq[4];
  {
    const __hip_bfloat16* qp = qkv + (rowbase + qg) * 3072 + h * 64 + hi * 8;
    bq[0] = *(const bf16x8*)(qp);
    bq[1] = *(const bf16x8*)(qp + 16);
    bq[2] = *(const bf16x8*)(qp + 32);
    bq[3] = *(const bf16x8*)(qp + 48);
  }

  const int jmax = 4 * qt + 3;

  {  // prologue: stage tile 0 into buffer 0
    const char* kb = (const char*)(qkv + rowbase * 3072 + 1024 + h * 64);
    async_copy16((char*)Ks[0] + tid * 16, kb + (size_t)krow * 6144 + kgch * 16);
    uint4 vv = *(const uint4*)(qkv + (rowbase + lane) * 3072 + 2048 + h * 64 + w * 8);
    const __hip_bfloat16* pv = (const __hip_bfloat16*)&vv;
    #pragma unroll
    for (int e = 0; e < 8; ++e) VT[0][(w * 8 + e) * VSTR + lane] = pv[e];
  }

  float mrow = NEG_BIG, plocal = 0.f;
  f32x16 oacc[2] = {};   // O^T: col q = l31, row d = dsub*32 + (r&3)+8*(r>>2)+4*hi
  int buf = 0;

  for (int j = 0; j <= jmax; ++j) {
    __syncthreads();  // staging of buf landed; prior readers of nbuf done
    const int nbuf = buf ^ 1;
    const int j0 = j * 64;
    const bool pre = (j < jmax);
    uint4 vv_next;
    if (pre) {  // prefetch tile j+1 into nbuf
      const int jn0 = j0 + 64;
      const char* kb = (const char*)(qkv + (rowbase + jn0) * 3072 + 1024 + h * 64);
      async_copy16((char*)Ks[nbuf] + tid * 16, kb + (size_t)krow * 6144 + kgch * 16);
      vv_next = *(const uint4*)(qkv + (rowbase + jn0 + lane) * 3072 + 2048 + h * 64 + w * 8);
    }

    #pragma unroll 2
    for (int sub = 0; sub < 2; ++sub) {
      const int j0s = j0 + sub * 32;
      if (j0s > wq_max) continue;            // fully-masked subtile (wave-uniform)

      // ---- S^T = K · Q^T  (A=Ks[key][d] swizzled, B=Q) ----
      f32x16 sacc = {};
      __builtin_amdgcn_s_setprio(1);
      #pragma unroll
      for (int kc = 0; kc < 4; ++kc) {
        int row = sub * 32 + l31;
        int ch = (2 * kc + hi) ^ (row & 7);
        bf16x8 ak = *(const bf16x8*)(Ks[buf] + row * 64 + ch * 8);
        sacc = __builtin_amdgcn_mfma_f32_32x32x16_bf16(ak, bq[kc], sacc, 0, 0, 0);
      }
      __builtin_amdgcn_s_setprio(0);

      // ---- mask + max ----
      float mt = NEG_BIG;
      const bool needc = (j0s + 31 > wq_min);
      if (allones) {
        if (needc) {
          #pragma unroll
          for (int r = 0; r < 16; ++r) {
            int key = j0s + (r & 3) + 8 * (r >> 2) + 4 * hi;
            float v = (key <= qg) ? sacc[r] : NEG_BIG;
            sacc[r] = v;
            mt = fmaxf(mt, v);
          }
        } else {
          #pragma unroll
          for (int r = 0; r < 16; ++r) mt = fmaxf(mt, sacc[r]);
        }
        mt *= SC2;  // scores kept raw; scale folded into exp fma
      } else {
        #pragma unroll
        for (int rr = 0; rr < 4; ++rr) {
          float4 mb4 = *(const float4*)(mbias + rowbase + j0s + rr * 8 + hi * 4);
          const float* mp = (const float*)&mb4;
          #pragma unroll
          for (int i = 0; i < 4; ++i) {
            int r = rr * 4 + i;
            int key = j0s + i + 8 * rr + 4 * hi;
            float v = fmaf(sacc[r], SC2, mp[i]);
            if (needc) v = (key <= qg) ? v : NEG_BIG;
            sacc[r] = v;
            mt = fmaxf(mt, v);
          }
        }
      }
      mt = fmaxf(mt, __shfl_xor(mt, 32));

      // ---- defer-max rescale (THR=8 in log2 domain) ----
      if (!__all(mt <= mrow + 8.f)) {
        float mn = fmaxf(mrow, mt);
        float a = __builtin_exp2f(mrow - mn);
        plocal *= a;
        #pragma unroll
        for (int d = 0; d < 2; ++d)
          #pragma unroll
          for (int r = 0; r < 16; ++r) oacc[d][r] *= a;
        mrow = mn;
      }

      // ---- exp + pack to bf16 pairs ----
      const float sfac = allones ? SC2 : 1.0f;
      float psl = 0.f;
      unsigned pk[8];
      #pragma unroll
      for (int r2 = 0; r2 < 8; ++r2) {
        float p0 = __builtin_exp2f(fmaf(sacc[2 * r2],     sfac, -mrow));
        float p1 = __builtin_exp2f(fmaf(sacc[2 * r2 + 1], sfac, -mrow));
        psl += p0 + p1;
        pk[r2] = pk2(p0, p1);
      }
      plocal += psl;

      // ---- in-register P exchange: hi-half swaps ----
      pl32swap(pk[0], pk[2]);
      pl32swap(pk[1], pk[3]);
      pl32swap(pk[4], pk[6]);
      pl32swap(pk[5], pk[7]);

      // ---- O^T += V^T · P  (A=VT[d][key], B=P[key][q]) ----
      __builtin_amdgcn_s_setprio(1);
      #pragma unroll
      for (int ks = 0; ks < 2; ++ks) {
        uint4 t = make_uint4(pk[ks * 4 + 0], pk[ks * 4 + 1],
                             pk[ks * 4 + 2], pk[ks * 4 + 3]);
        bf16x8 bp;
        __builtin_memcpy(&bp, &t, 16);
        #pragma unroll
        for (int d = 0; d < 2; ++d) {
          bf16x8 av = *(const bf16x8*)(VT[buf] + (d * 32 + l31) * VSTR +
                                       sub * 32 + ks * 16 + hi * 8);
          oacc[d] = __builtin_amdgcn_mfma_f32_32x32x16_bf16(av, bp, oacc[d], 0, 0, 0);
        }
      }
      __builtin_amdgcn_s_setprio(0);
    }

    if (pre) {  // finish staging of nbuf (VT)
      const __hip_bfloat16* pv = (const __hip_bfloat16*)&vv_next;
      #pragma unroll
      for (int e = 0; e < 8; ++e) VT[nbuf][(w * 8 + e) * VSTR + lane] = pv[e];
    }
    buf = nbuf;
  }

  {  // epilogue: reduce l across hi halves, divide, store
    float l = plocal + __shfl_xor(plocal, 32);
    float linv = (l > 0.f) ? 1.f / l : 0.f;
    __hip_bfloat16* ob = outp + (rowbase + qg) * 1024 + h * 64;
    #pragma unroll
    for (int d = 0; d < 2; ++d)
      #pragma unroll
      for (int rr = 0; rr < 4; ++rr) {
        bf16x4v ov;
        ov[0] = (__bf16)(oacc[d][rr * 4 + 0] * linv);
        ov[1] = (__bf16)(oacc[d][rr * 4 + 1] * linv);
        ov[2] = (__bf16)(oacc[d][rr * 4 + 2] * linv);
        ov[3] = (__bf16)(oacc[d][rr * 4 + 3] * linv);
        *(bf16x4v*)(ob + d * 32 + rr * 8 + hi * 4) = ov;
      }
  }
}

extern "C" void kernel_launch(void* const* d_in, const int* in_sizes, int n_in,
                              void* d_out, int out_size, void* d_ws, size_t ws_size,
                              hipStream_t stream) {
  const bool merged = (ws_size >= (80ull << 20));
  char* ws = (char*)d_ws;
  int*            flag   = (int*)ws;
  float*          bq     = (float*)(ws + 1024);
  float*          bp     = (float*)(ws + 16384);
  float*          mbias  = (float*)(ws + 32768);
  unsigned short* WqkvTu = (unsigned short*)(ws + 65536);
  unsigned short* WprojTu= (unsigned short*)(ws + 65536 + 6291456);
  char*           big    = ws + 65536 + 8388608;
  __hip_bfloat16* qkv    = (__hip_bfloat16*)big;
  __hip_bfloat16* attno  = (__hip_bfloat16*)(big + (merged ? 50331648u : 12582912u));

  probe_dtype<<<1, 256, 0, stream>>>((const unsigned short*)d_in[0], flag);
  convert_to_f32<<<12, 256, 0, stream>>>(d_in[3], bq, flag, 3072);
  convert_to_f32<<<4, 256, 0, stream>>>(d_in[5], bp, flag, 1024);
  mask_bias<<<(B_ * S_) / 256, 256, 0, stream>>>((const int*)d_in[1], mbias, flag, B_ * S_);
  transpose_conv<<<dim3(96, 32), 256, 0, stream>>>(d_in[2], WqkvTu, flag, 1024, 3072);
  transpose_conv<<<dim3(32, 32), 256, 0, stream>>>(d_in[4], WprojTu, flag, 1024, 1024);

  const int nchunk = merged ? 1 : B_;
  const int bsz = merged ? B_ : 1;
  const int Mc = bsz * S_;
  for (int c = 0; c < nchunk; ++c) {
    long long off = (long long)c * S_ * E_;
    gemm_x_w<<<dim3(Mc / 128, 3072 / 128), 256, 0, stream>>>(
        d_in[0], off, (const __hip_bfloat16*)WqkvTu, bq, flag, qkv, Mc, 3072, 1024);
    attn_flash<<<dim3(S_ / 256, bsz * H_), 512, 0, stream>>>(
        qkv, mbias + (size_t)c * S_, flag, attno);
    gemm_p_out<<<dim3(Mc / 128, 1024 / 128), 256, 0, stream>>>(
        attno, (const __hip_bfloat16*)WprojTu, bp, flag, d_out, off, Mc, 1024, 1024);
  }
}

// Round 2
// 321.990 us; speedup vs baseline: 1.1981x; 1.1323x over previous
//
#include <hip/hip_runtime.h>
#include <hip/hip_bf16.h>
#include <cstdint>
#include <cstddef>

#define B_ 4
#define S_ 2048
#define E_ 1024
#define H_ 16
#define D_ 64
#define NEG_BIG (-1e30f)
#define SC2 0.18033688011112043f   /* 0.125 * log2(e) */

typedef __bf16 bf16x8 __attribute__((ext_vector_type(8)));
typedef __bf16 bf16x4v __attribute__((ext_vector_type(4)));
typedef float f32x4 __attribute__((ext_vector_type(4)));
typedef float f32x16 __attribute__((ext_vector_type(16)));

__device__ __forceinline__ void async_copy16(void* lds, const void* g) {
  __builtin_amdgcn_global_load_lds(
      (const __attribute__((address_space(1))) void*)g,
      (__attribute__((address_space(3))) void*)lds, 16, 0, 0);
}

__device__ __forceinline__ float bfu2f(unsigned short u) {
  unsigned v = ((unsigned)u) << 16;
  float f;
  __builtin_memcpy(&f, &v, 4);
  return f;
}
__device__ __forceinline__ unsigned short f2bfu(float f) {
  __hip_bfloat16 h = __float2bfloat16(f);  // RNE
  unsigned short u;
  __builtin_memcpy(&u, &h, 2);
  return u;
}
__device__ __forceinline__ unsigned pk2(float a, float b) {
  return (unsigned)f2bfu(a) | ((unsigned)f2bfu(b) << 16);
}

// swap hi 32 lanes of a with lo 32 lanes of b (v_permlane32_swap_b32)
__device__ __forceinline__ void pl32swap(unsigned& a, unsigned& b) {
#if defined(__has_builtin)
#if __has_builtin(__builtin_amdgcn_permlane32_swap)
  typedef int i32x2 __attribute__((ext_vector_type(2)));
  i32x2 r = __builtin_amdgcn_permlane32_swap((int)a, (int)b, false, false);
  a = (unsigned)r[0];
  b = (unsigned)r[1];
  return;
#else
  asm("v_permlane32_swap_b32 %0, %1" : "+v"(a), "+v"(b));
  return;
#endif
#else
  asm("v_permlane32_swap_b32 %0, %1" : "+v"(a), "+v"(b));
#endif
}

// ---------------- dtype probe (proven) ----------------
__global__ __launch_bounds__(256) void probe_dtype(
    const unsigned short* __restrict__ xr, int* __restrict__ flagp) {
  __shared__ int cnt;
  if (threadIdx.x == 0) cnt = 0;
  __syncthreads();
  int bad = 0;
  for (int i = 0; i < 32; ++i) {
    unsigned short u = xr[(threadIdx.x * 32 + i) * 2];
    int e = (u >> 7) & 0xFF;
    if (e == 0xFF || e >= 0x90 || (e != 0 && e <= 0x60)) bad++;
  }
  atomicAdd(&cnt, bad);
  __syncthreads();
  if (threadIdx.x == 0) {
    flagp[0] = (cnt > 512) ? 0 : 1;  // 0=fp32, 1=bf16
    flagp[1] = 1;                    // all-ones-mask flag, cleared by mask_bias
  }
}

__global__ __launch_bounds__(256) void convert_to_f32(
    const void* __restrict__ in, float* __restrict__ out,
    const int* __restrict__ flagp, int n) {
  int i = blockIdx.x * blockDim.x + threadIdx.x;
  if (i >= n) return;
  out[i] = (*flagp == 0) ? ((const float*)in)[i]
                         : bfu2f(((const unsigned short*)in)[i]);
}

// pad mask -> additive bias (0 / -1e30); also detect all-ones mask
__global__ __launch_bounds__(256) void mask_bias(
    const int* __restrict__ am, float* __restrict__ mb,
    int* __restrict__ flagp, int n) {
  int i = blockIdx.x * blockDim.x + threadIdx.x;
  if (i < n) {
    int a = am[i];
    mb[i] = a ? 0.f : NEG_BIG;
    if (a == 0) atomicAnd(flagp + 1, 0);
  }
}

// transpose + convert: out_bf16[C][R] = in[R][C]   (proven)
__global__ __launch_bounds__(256) void transpose_conv(
    const void* __restrict__ in, unsigned short* __restrict__ out,
    const int* __restrict__ flagp, int R, int C) {
  __shared__ unsigned short t[32][33];
  const int flag = *flagp;
  const int c0 = blockIdx.x * 32, r0 = blockIdx.y * 32;
  const int lc = threadIdx.x & 31, lr = threadIdx.x >> 5;
  for (int i = 0; i < 4; ++i) {
    int r = lr + i * 8;
    size_t idx = (size_t)(r0 + r) * C + c0 + lc;
    t[r][lc] = (flag == 0) ? f2bfu(((const float*)in)[idx])
                           : ((const unsigned short*)in)[idx];
  }
  __syncthreads();
  for (int i = 0; i < 4; ++i) {
    int r = lr + i * 8;
    out[(size_t)(c0 + r) * R + r0 + lc] = t[lc][r];
  }
}

// -------- GEMM1: qkv = x(fp32|bf16) @ WqkvT^T + bias, out bf16 --------
// 1D grid, XCD-chunked: XCD k owns m-tiles [k*mloc, (k+1)*mloc) for all n
// (A-panel ~2MB stays L2-resident, reused by every n-tile on that XCD).
__global__ __launch_bounds__(256) void gemm_x_w(
    const void* __restrict__ Xin, long long xoff,
    const __hip_bfloat16* __restrict__ Bt,
    const float* __restrict__ bias,
    const int* __restrict__ flagp,
    __hip_bfloat16* __restrict__ C,
    int M, int N, int K) {
  __shared__ __align__(16) __hip_bfloat16 As[128 * 32];
  __shared__ __align__(16) __hip_bfloat16 Bs[128 * 32];
  const int flag = *flagp;
  const int tid = threadIdx.x;
  const int lin = blockIdx.x;
  const int mtiles = M >> 7;
  const int mloc = mtiles >> 3;                 // m-tiles per XCD (pow2)
  const int msh = 31 - __builtin_clz(mloc);
  const int xcd = lin & 7, idx = lin >> 3;
  const int m0 = (xcd * mloc + (idx & (mloc - 1))) << 7;
  const int n0 = (idx >> msh) << 7;
  const int w = tid >> 6, lane = tid & 63;
  const int wm = (w & 1) * 64, wn = (w >> 1) * 64;
  const int lm = lane & 15, kg = lane >> 4;
  const int e0 = tid * 8, e1 = tid * 8 + 2048;
  const int ra = tid >> 2;
  const int sw = ((tid >> 3) & 3);
  const int ca = ((tid & 3) ^ sw) * 8;

  f32x4 acc[4][4] = {};

  for (int k0 = 0; k0 < K; k0 += 32) {
    uint4 aw0, aw1;
    if (flag == 0) {
      const float* A32 = (const float*)Xin + xoff;
      float4 f0 = *(const float4*)(A32 + (size_t)(m0 + ra) * K + k0 + ca);
      float4 f1 = *(const float4*)(A32 + (size_t)(m0 + ra) * K + k0 + ca + 4);
      float4 f2 = *(const float4*)(A32 + (size_t)(m0 + ra + 64) * K + k0 + ca);
      float4 f3 = *(const float4*)(A32 + (size_t)(m0 + ra + 64) * K + k0 + ca + 4);
      aw0 = make_uint4(pk2(f0.x, f0.y), pk2(f0.z, f0.w), pk2(f1.x, f1.y), pk2(f1.z, f1.w));
      aw1 = make_uint4(pk2(f2.x, f2.y), pk2(f2.z, f2.w), pk2(f3.x, f3.y), pk2(f3.z, f3.w));
    } else {
      const unsigned short* A16 = (const unsigned short*)Xin + xoff;
      aw0 = *(const uint4*)(A16 + (size_t)(m0 + ra) * K + k0 + ca);
      aw1 = *(const uint4*)(A16 + (size_t)(m0 + ra + 64) * K + k0 + ca);
    }
    __syncthreads();
    *(uint4*)(As + e0) = aw0;
    *(uint4*)(As + e1) = aw1;
    for (int c = 0; c < 2; ++c) {
      int o = tid * 16 + c * 4096;
      int row = o >> 6, chp = (o >> 4) & 3;
      int gch = chp ^ ((row >> 1) & 3);
      async_copy16((char*)Bs + o, (const char*)(Bt + (size_t)(n0 + row) * K + k0 + gch * 8));
    }
    __syncthreads();
    bf16x8 af[4], bfrag[4];
    for (int t = 0; t < 4; ++t) {
      int rt = wm + t * 16 + lm;
      int ch = kg ^ ((rt >> 1) & 3);
      af[t] = *(const bf16x8*)(As + rt * 32 + ch * 8);
    }
    for (int t = 0; t < 4; ++t) {
      int rt = wn + t * 16 + lm;
      int ch = kg ^ ((rt >> 1) & 3);
      bfrag[t] = *(const bf16x8*)(Bs + rt * 32 + ch * 8);
    }
    for (int tm = 0; tm < 4; ++tm)
      for (int tn = 0; tn < 4; ++tn)
        acc[tm][tn] = __builtin_amdgcn_mfma_f32_16x16x32_bf16(af[tm], bfrag[tn], acc[tm][tn], 0, 0, 0);
  }

  for (int tn = 0; tn < 4; ++tn) {
    int col = n0 + wn + tn * 16 + lm;
    float bv = bias[col];
    for (int tm = 0; tm < 4; ++tm) {
      int rbase = m0 + wm + tm * 16 + kg * 4;
      for (int r = 0; r < 4; ++r)
        C[(size_t)(rbase + r) * N + col] = __float2bfloat16(acc[tm][tn][r] + bv);
    }
  }
}

// -------- GEMM2: out = attno @ WprojT^T + bias; out dtype by flag --------
__global__ __launch_bounds__(256) void gemm_p_out(
    const __hip_bfloat16* __restrict__ A,
    const __hip_bfloat16* __restrict__ Bt,
    const float* __restrict__ bias,
    const int* __restrict__ flagp,
    void* __restrict__ Cv, long long coff,
    int M, int N, int K) {
  __shared__ __align__(16) __hip_bfloat16 As[128 * 32];
  __shared__ __align__(16) __hip_bfloat16 Bs[128 * 32];
  const int flag = *flagp;
  const int tid = threadIdx.x;
  const int lin = blockIdx.x;
  const int mtiles = M >> 7;
  const int mloc = mtiles >> 3;
  const int msh = 31 - __builtin_clz(mloc);
  const int xcd = lin & 7, idx = lin >> 3;
  const int m0 = (xcd * mloc + (idx & (mloc - 1))) << 7;
  const int n0 = (idx >> msh) << 7;
  const int w = tid >> 6, lane = tid & 63;
  const int wm = (w & 1) * 64, wn = (w >> 1) * 64;
  const int lm = lane & 15, kg = lane >> 4;

  f32x4 acc[4][4] = {};

  for (int k0 = 0; k0 < K; k0 += 32) {
    __syncthreads();
    for (int c = 0; c < 2; ++c) {
      int o = tid * 16 + c * 4096;
      int row = o >> 6, chp = (o >> 4) & 3;
      int gch = chp ^ ((row >> 1) & 3);
      async_copy16((char*)As + o, (const char*)(A + (size_t)(m0 + row) * K + k0 + gch * 8));
      async_copy16((char*)Bs + o, (const char*)(Bt + (size_t)(n0 + row) * K + k0 + gch * 8));
    }
    __syncthreads();
    bf16x8 af[4], bfrag[4];
    for (int t = 0; t < 4; ++t) {
      int rt = wm + t * 16 + lm;
      int ch = kg ^ ((rt >> 1) & 3);
      af[t] = *(const bf16x8*)(As + rt * 32 + ch * 8);
    }
    for (int t = 0; t < 4; ++t) {
      int rt = wn + t * 16 + lm;
      int ch = kg ^ ((rt >> 1) & 3);
      bfrag[t] = *(const bf16x8*)(Bs + rt * 32 + ch * 8);
    }
    for (int tm = 0; tm < 4; ++tm)
      for (int tn = 0; tn < 4; ++tn)
        acc[tm][tn] = __builtin_amdgcn_mfma_f32_16x16x32_bf16(af[tm], bfrag[tn], acc[tm][tn], 0, 0, 0);
  }

  for (int tn = 0; tn < 4; ++tn) {
    int col = n0 + wn + tn * 16 + lm;
    float bv = bias[col];
    for (int tm = 0; tm < 4; ++tm) {
      int rbase = m0 + wm + tm * 16 + kg * 4;
      for (int r = 0; r < 4; ++r) {
        float v = acc[tm][tn][r] + bv;
        size_t idx2 = (size_t)coff + (size_t)(rbase + r) * N + col;
        if (flag == 0) ((float*)Cv)[idx2] = v;
        else           ((unsigned short*)Cv)[idx2] = f2bfu(v);
      }
    }
  }
}

// -------- causal flash attention v5 ----------------------------------------
// 256 threads (4 waves), 128 q/block (32 q/wave), 32-key subtiles.
// K fetched DIRECTLY global->VGPR as MFMA A-fragments, software-pipelined
// one subtile ahead (ka/kb parity) -- no K LDS, no K barrier coupling.
// Only V goes through LDS (transposed, double-buffered, 1 barrier/tile).
// XCD-chunked block swizzle keeps each (b,h)'s K/V panels L2-hot.
#define VSTR 72
__device__ __forceinline__ void attn_subtile(
    int j0s, int wq_min, int wq_max, int qg, int allones,
    const char* kbyte, const float* mbrow,
    uint4& kc0, uint4& kc1, uint4& kc2, uint4& kc3,
    uint4& kn0, uint4& kn1, uint4& kn2, uint4& kn3,
    const bf16x8* bq, const __hip_bfloat16* VTb, int hi,
    float& mrow, float& plocal, f32x16& o0, f32x16& o1) {
  if (j0s > wq_max) return;
  {  // prefetch next subtile's K fragments (registers)
    const int jn = j0s + 32;
    if (jn <= wq_max) {
      const char* kp = kbyte + (size_t)jn * 6144;
      kn0 = *(const uint4*)(kp);
      kn1 = *(const uint4*)(kp + 32);
      kn2 = *(const uint4*)(kp + 64);
      kn3 = *(const uint4*)(kp + 96);
    }
  }
  bf16x8 a0, a1, a2, a3;
  __builtin_memcpy(&a0, &kc0, 16);
  __builtin_memcpy(&a1, &kc1, 16);
  __builtin_memcpy(&a2, &kc2, 16);
  __builtin_memcpy(&a3, &kc3, 16);

  // ---- S^T = K · Q^T ----
  f32x16 sacc = {};
  __builtin_amdgcn_s_setprio(1);
  sacc = __builtin_amdgcn_mfma_f32_32x32x16_bf16(a0, bq[0], sacc, 0, 0, 0);
  sacc = __builtin_amdgcn_mfma_f32_32x32x16_bf16(a1, bq[1], sacc, 0, 0, 0);
  sacc = __builtin_amdgcn_mfma_f32_32x32x16_bf16(a2, bq[2], sacc, 0, 0, 0);
  sacc = __builtin_amdgcn_mfma_f32_32x32x16_bf16(a3, bq[3], sacc, 0, 0, 0);
  __builtin_amdgcn_s_setprio(0);

  // ---- mask + max ----
  float mt = NEG_BIG;
  const bool needc = (j0s + 31 > wq_min);
  if (allones) {
    if (needc) {
      #pragma unroll
      for (int r = 0; r < 16; ++r) {
        int key = j0s + (r & 3) + 8 * (r >> 2) + 4 * hi;
        float v = (key <= qg) ? sacc[r] : NEG_BIG;
        sacc[r] = v;
        mt = fmaxf(mt, v);
      }
    } else {
      #pragma unroll
      for (int r = 0; r < 16; ++r) mt = fmaxf(mt, sacc[r]);
    }
    mt *= SC2;  // scores stay raw; scale folded into exp fma
  } else {
    #pragma unroll
    for (int rr = 0; rr < 4; ++rr) {
      float4 mb4 = *(const float4*)(mbrow + j0s + rr * 8 + hi * 4);
      const float* mp = (const float*)&mb4;
      #pragma unroll
      for (int i = 0; i < 4; ++i) {
        int r = rr * 4 + i;
        int key = j0s + i + 8 * rr + 4 * hi;
        float v = fmaf(sacc[r], SC2, mp[i]);
        if (needc) v = (key <= qg) ? v : NEG_BIG;
        sacc[r] = v;
        mt = fmaxf(mt, v);
      }
    }
  }
  mt = fmaxf(mt, __shfl_xor(mt, 32));

  // ---- defer-max rescale (THR=8, log2 domain) ----
  if (!__all(mt <= mrow + 8.f)) {
    float mn = fmaxf(mrow, mt);
    float a = __builtin_exp2f(mrow - mn);
    plocal *= a;
    #pragma unroll
    for (int r = 0; r < 16; ++r) { o0[r] *= a; o1[r] *= a; }
    mrow = mn;
  }

  // ---- exp + pack ----
  const float sfac = allones ? SC2 : 1.0f;
  float psl = 0.f;
  unsigned pk[8];
  #pragma unroll
  for (int r2 = 0; r2 < 8; ++r2) {
    float p0 = __builtin_exp2f(fmaf(sacc[2 * r2],     sfac, -mrow));
    float p1 = __builtin_exp2f(fmaf(sacc[2 * r2 + 1], sfac, -mrow));
    psl += p0 + p1;
    pk[r2] = pk2(p0, p1);
  }
  plocal += psl;

  // ---- in-register P exchange ----
  pl32swap(pk[0], pk[2]);
  pl32swap(pk[1], pk[3]);
  pl32swap(pk[4], pk[6]);
  pl32swap(pk[5], pk[7]);

  // ---- O^T += V^T · P ----
  __builtin_amdgcn_s_setprio(1);
  #pragma unroll
  for (int ks = 0; ks < 2; ++ks) {
    uint4 t = make_uint4(pk[ks * 4 + 0], pk[ks * 4 + 1],
                         pk[ks * 4 + 2], pk[ks * 4 + 3]);
    bf16x8 bp;
    __builtin_memcpy(&bp, &t, 16);
    bf16x8 av0 = *(const bf16x8*)(VTb + ks * 16);
    bf16x8 av1 = *(const bf16x8*)(VTb + 32 * VSTR + ks * 16);
    o0 = __builtin_amdgcn_mfma_f32_32x32x16_bf16(av0, bp, o0, 0, 0, 0);
    o1 = __builtin_amdgcn_mfma_f32_32x32x16_bf16(av1, bp, o1, 0, 0, 0);
  }
  __builtin_amdgcn_s_setprio(0);
}

__global__ __launch_bounds__(256, 3) void attn_flash(
    const __hip_bfloat16* __restrict__ qkv,  // [bsz*S][3072]
    const float* __restrict__ mbias,         // [bsz*S] 0 / -1e30
    const int* __restrict__ flags,           // flags[1]: mask all-ones
    __hip_bfloat16* __restrict__ outp) {     // [bsz*S][1024]
  __shared__ __align__(16) __hip_bfloat16 VT[2][64 * VSTR]; // [d][key]

  const int tid = threadIdx.x;
  // XCD-chunked swizzle: XCD k owns bh in [k*bhloc,(k+1)*bhloc), all q-tiles;
  // within XCD, heavy q-tiles (large qt) dispatched first (LPT).
  const int lin = blockIdx.x;
  const int nbh = gridDim.x >> 4;          // 16 q-blocks of 128 rows
  const int bhloc = nbh >> 3;
  const int bsh = 31 - __builtin_clz(bhloc);
  const int xcd = lin & 7, idx = lin >> 3;
  const int bh = xcd * bhloc + (idx & (bhloc - 1));
  const int bx = idx >> bsh;
  const int qt = 15 - bx;                  // LPT: heavy first
  const int b = bh >> 4, h = bh & 15;
  const int q0 = qt * 128;
  const size_t rowbase = (size_t)b * S_;
  const int w = tid >> 6, lane = tid & 63;
  const int l31 = lane & 31, hi = lane >> 5;
  const int qg = q0 + w * 32 + l31;
  const int wq_min = q0 + w * 32, wq_max = wq_min + 31;
  const int allones = flags[1];
  const float* mbrow = mbias + rowbase;

  // per-lane K base: row l31, d-offset hi*8 (fragment kc at +kc*32B)
  const char* kbyte = (const char*)(qkv + (rowbase + l31) * 3072 + 1024 + h * 64 + hi * 8);

  // Q fragments: lane holds Q[qg][kc*16 + hi*8 + e]
  bf16x8 bq[4];
  {
    const __hip_bfloat16* qp = qkv + (rowbase + qg) * 3072 + h * 64 + hi * 8;
    bq[0] = *(const bf16x8*)(qp);
    bq[1] = *(const bf16x8*)(qp + 16);
    bq[2] = *(const bf16x8*)(qp + 32);
    bq[3] = *(const bf16x8*)(qp + 48);
  }

  const int jmax = 2 * qt + 1;

  // prologue: K subtile 0 into ka; V tile 0 into VT[0]
  uint4 ka0, ka1, ka2, ka3, kb0, kb1, kb2, kb3;
  ka0 = *(const uint4*)(kbyte);
  ka1 = *(const uint4*)(kbyte + 32);
  ka2 = *(const uint4*)(kbyte + 64);
  ka3 = *(const uint4*)(kbyte + 96);
  {
    const __hip_bfloat16* vp = qkv + (rowbase + lane) * 3072 + 2048 + h * 64 + w * 16;
    uint4 v0 = *(const uint4*)(vp);
    uint4 v1 = *(const uint4*)(vp + 8);
    const __hip_bfloat16* p0 = (const __hip_bfloat16*)&v0;
    const __hip_bfloat16* p1 = (const __hip_bfloat16*)&v1;
    #pragma unroll
    for (int e = 0; e < 8; ++e) {
      VT[0][(w * 16 + e) * VSTR + lane] = p0[e];
      VT[0][(w * 16 + 8 + e) * VSTR + lane] = p1[e];
    }
  }

  float mrow = NEG_BIG, plocal = 0.f;
  f32x16 o0 = {}, o1 = {};   // O^T: col q=l31, row d = dblk*32 + (r&3)+8*(r>>2)+4*hi
  int buf = 0;

  for (int j = 0; j <= jmax; ++j) {
    __syncthreads();  // VT[buf] staged; prior readers of nbuf done
    const int nbuf = buf ^ 1;
    const int j0 = j * 64;
    const bool pre = (j < jmax);
    uint4 vva, vvb;
    if (pre) {
      const __hip_bfloat16* vp = qkv + (rowbase + j0 + 64 + lane) * 3072 + 2048 + h * 64 + w * 16;
      vva = *(const uint4*)(vp);
      vvb = *(const uint4*)(vp + 8);
    }
    const __hip_bfloat16* vb0 = VT[buf] + l31 * VSTR + hi * 8;

    attn_subtile(j0, wq_min, wq_max, qg, allones, kbyte, mbrow,
                 ka0, ka1, ka2, ka3, kb0, kb1, kb2, kb3,
                 bq, vb0, hi, mrow, plocal, o0, o1);
    attn_subtile(j0 + 32, wq_min, wq_max, qg, allones, kbyte, mbrow,
                 kb0, kb1, kb2, kb3, ka0, ka1, ka2, ka3,
                 bq, vb0 + 32, hi, mrow, plocal, o0, o1);

    if (pre) {  // finish staging of nbuf (VT)
      const __hip_bfloat16* p0 = (const __hip_bfloat16*)&vva;
      const __hip_bfloat16* p1 = (const __hip_bfloat16*)&vvb;
      #pragma unroll
      for (int e = 0; e < 8; ++e) {
        VT[nbuf][(w * 16 + e) * VSTR + lane] = p0[e];
        VT[nbuf][(w * 16 + 8 + e) * VSTR + lane] = p1[e];
      }
    }
    buf = nbuf;
  }

  {  // epilogue: reduce l across hi halves, divide, store
    float l = plocal + __shfl_xor(plocal, 32);
    float linv = (l > 0.f) ? 1.f / l : 0.f;
    __hip_bfloat16* ob = outp + (rowbase + qg) * 1024 + h * 64;
    #pragma unroll
    for (int rr = 0; rr < 4; ++rr) {
      bf16x4v ov;
      ov[0] = (__bf16)(o0[rr * 4 + 0] * linv);
      ov[1] = (__bf16)(o0[rr * 4 + 1] * linv);
      ov[2] = (__bf16)(o0[rr * 4 + 2] * linv);
      ov[3] = (__bf16)(o0[rr * 4 + 3] * linv);
      *(bf16x4v*)(ob + rr * 8 + hi * 4) = ov;
      bf16x4v ow;
      ow[0] = (__bf16)(o1[rr * 4 + 0] * linv);
      ow[1] = (__bf16)(o1[rr * 4 + 1] * linv);
      ow[2] = (__bf16)(o1[rr * 4 + 2] * linv);
      ow[3] = (__bf16)(o1[rr * 4 + 3] * linv);
      *(bf16x4v*)(ob + 32 + rr * 8 + hi * 4) = ow;
    }
  }
}

extern "C" void kernel_launch(void* const* d_in, const int* in_sizes, int n_in,
                              void* d_out, int out_size, void* d_ws, size_t ws_size,
                              hipStream_t stream) {
  const bool merged = (ws_size >= (80ull << 20));
  char* ws = (char*)d_ws;
  int*            flag   = (int*)ws;
  float*          bq     = (float*)(ws + 1024);
  float*          bp     = (float*)(ws + 16384);
  float*          mbias  = (float*)(ws + 32768);
  unsigned short* WqkvTu = (unsigned short*)(ws + 65536);
  unsigned short* WprojTu= (unsigned short*)(ws + 65536 + 6291456);
  char*           big    = ws + 65536 + 8388608;
  __hip_bfloat16* qkv    = (__hip_bfloat16*)big;
  __hip_bfloat16* attno  = (__hip_bfloat16*)(big + (merged ? 50331648u : 12582912u));

  probe_dtype<<<1, 256, 0, stream>>>((const unsigned short*)d_in[0], flag);
  convert_to_f32<<<12, 256, 0, stream>>>(d_in[3], bq, flag, 3072);
  convert_to_f32<<<4, 256, 0, stream>>>(d_in[5], bp, flag, 1024);
  mask_bias<<<(B_ * S_) / 256, 256, 0, stream>>>((const int*)d_in[1], mbias, flag, B_ * S_);
  transpose_conv<<<dim3(96, 32), 256, 0, stream>>>(d_in[2], WqkvTu, flag, 1024, 3072);
  transpose_conv<<<dim3(32, 32), 256, 0, stream>>>(d_in[4], WprojTu, flag, 1024, 1024);

  const int nchunk = merged ? 1 : B_;
  const int bsz = merged ? B_ : 1;
  const int Mc = bsz * S_;
  for (int c = 0; c < nchunk; ++c) {
    long long off = (long long)c * S_ * E_;
    gemm_x_w<<<dim3((Mc / 128) * (3072 / 128)), 256, 0, stream>>>(
        d_in[0], off, (const __hip_bfloat16*)WqkvTu, bq, flag, qkv, Mc, 3072, 1024);
    attn_flash<<<dim3((S_ / 128) * (bsz * H_)), 256, 0, stream>>>(
        qkv, mbias + (size_t)c * S_, flag, attno);
    gemm_p_out<<<dim3((Mc / 128) * (1024 / 128)), 256, 0, stream>>>(
        attno, (const __hip_bfloat16*)WprojTu, bp, flag, d_out, off, Mc, 1024, 1024);
  }
}